// Round 3
// baseline (404.270 us; speedup 1.0000x reference)
//
#include <hip/hip_runtime.h>
#include <hip/hip_bf16.h>
#include <math.h>

#define NPOS 2048
#define CH   512
#define KATT 128
#define NHEAD 8

// ---------------------------------------------------------------------------
// GroupNorm: 32 groups of 16 channels x 2048. One block per group.
// ---------------------------------------------------------------------------
__global__ __launch_bounds__(256) void gnorm_k(const float* __restrict__ x,
    const float* __restrict__ gw, const float* __restrict__ gb,
    float* __restrict__ hout) {
  const int g = blockIdx.x;
  const float* xp = x + g * 16 * NPOS;
  float s = 0.f, ss = 0.f;
  for (int i = threadIdx.x; i < 16 * NPOS; i += 256) {
    float v = xp[i];
    s += v;
    ss += v * v;
  }
  __shared__ float rs[256], rq[256];
  rs[threadIdx.x] = s;
  rq[threadIdx.x] = ss;
  __syncthreads();
  for (int off = 128; off > 0; off >>= 1) {
    if (threadIdx.x < (unsigned)off) {
      rs[threadIdx.x] += rs[threadIdx.x + off];
      rq[threadIdx.x] += rq[threadIdx.x + off];
    }
    __syncthreads();
  }
  const float inv_n = 1.f / (16.f * NPOS);
  const float mu = rs[0] * inv_n;
  const float var = rq[0] * inv_n - mu * mu;
  const float rstd = rsqrtf(var + 1e-6f);
  float* hp = hout + g * 16 * NPOS;
  for (int i = threadIdx.x; i < 16 * NPOS; i += 256) {
    int ch = g * 16 + (i >> 11);
    hp[i] = (xp[i] - mu) * rstd * gw[ch] + gb[ch];
  }
}

// ---------------------------------------------------------------------------
// GEMM producing TRANSPOSED output: out_t[n][c] = bias[c] + sum_cin w[c][cin]*h[cin][n]
// h is (CH, NPOS) row-major. w is (CH out, CH in) row-major. out_t is (NPOS, CH).
// Tile 64(n) x 64(c), K-tile 16, 256 threads, 4x4 micro-tile per thread.
// ---------------------------------------------------------------------------
__global__ __launch_bounds__(256) void gemm_t_k(const float* __restrict__ hbuf,
    const float* __restrict__ w, const float* __restrict__ bias,
    float* __restrict__ out_t) {
  __shared__ float Hs[16][64];
  __shared__ float Ws[16][64];
  const int nBase = blockIdx.x * 64;
  const int cBase = blockIdx.y * 64;
  const int tx = threadIdx.x & 15;   // c-dir
  const int ty = threadIdx.x >> 4;   // n-dir
  const int ldc = threadIdx.x >> 2;        // 0..63
  const int ldk = (threadIdx.x & 3) << 2;  // 0,4,8,12
  float acc[4][4] = {};
  for (int k0 = 0; k0 < CH; k0 += 16) {
#pragma unroll
    for (int i = 0; i < 4; ++i) {
      int f = threadIdx.x + 256 * i;
      Hs[f >> 6][f & 63] = hbuf[(k0 + (f >> 6)) * NPOS + nBase + (f & 63)];
    }
    {
      const float4 wv = *(const float4*)&w[(cBase + ldc) * CH + k0 + ldk];
      Ws[ldk][ldc] = wv.x;
      Ws[ldk + 1][ldc] = wv.y;
      Ws[ldk + 2][ldc] = wv.z;
      Ws[ldk + 3][ldc] = wv.w;
    }
    __syncthreads();
#pragma unroll
    for (int kk = 0; kk < 16; ++kk) {
      float hv[4], wv2[4];
#pragma unroll
      for (int j = 0; j < 4; ++j) hv[j] = Hs[kk][ty + 16 * j];
#pragma unroll
      for (int j = 0; j < 4; ++j) wv2[j] = Ws[kk][tx + 16 * j];
#pragma unroll
      for (int a = 0; a < 4; ++a)
#pragma unroll
        for (int b = 0; b < 4; ++b)
          acc[a][b] += hv[a] * wv2[b];
    }
    __syncthreads();
  }
#pragma unroll
  for (int a = 0; a < 4; ++a) {
    const int n = nBase + ty + 16 * a;
#pragma unroll
    for (int b = 0; b < 4; ++b) {
      const int c = cBase + tx + 16 * b;
      out_t[n * CH + c] = acc[a][b] + bias[c];
    }
  }
}

// ---------------------------------------------------------------------------
// Final GEMM + residual: out[c][n] = x[c][n] + bp[c] + sum_s wpp[c][s]*ot[n][s]
// ot is (NPOS, CH) row-major; wpp is (CH, CH) row-major (already permuted).
// out is (CH, NPOS).
// ---------------------------------------------------------------------------
__global__ __launch_bounds__(256) void gemm_r_k(const float* __restrict__ ot,
    const float* __restrict__ wpp, const float* __restrict__ bp,
    const float* __restrict__ x, float* __restrict__ out) {
  __shared__ float As[16][64];
  __shared__ float Bs[16][64];
  const int nBase = blockIdx.x * 64;
  const int cBase = blockIdx.y * 64;
  const int tx = threadIdx.x & 15;   // n-dir
  const int ty = threadIdx.x >> 4;   // c-dir
  const int ldr = threadIdx.x >> 2;        // 0..63
  const int ldk = (threadIdx.x & 3) << 2;  // 0,4,8,12
  float acc[4][4] = {};
  for (int k0 = 0; k0 < CH; k0 += 16) {
    {
      const float4 av = *(const float4*)&wpp[(cBase + ldr) * CH + k0 + ldk];
      As[ldk][ldr] = av.x;
      As[ldk + 1][ldr] = av.y;
      As[ldk + 2][ldr] = av.z;
      As[ldk + 3][ldr] = av.w;
      const float4 bv = *(const float4*)&ot[(nBase + ldr) * CH + k0 + ldk];
      Bs[ldk][ldr] = bv.x;
      Bs[ldk + 1][ldr] = bv.y;
      Bs[ldk + 2][ldr] = bv.z;
      Bs[ldk + 3][ldr] = bv.w;
    }
    __syncthreads();
#pragma unroll
    for (int kk = 0; kk < 16; ++kk) {
      float av2[4], bv2[4];
#pragma unroll
      for (int j = 0; j < 4; ++j) av2[j] = As[kk][ty + 16 * j];
#pragma unroll
      for (int j = 0; j < 4; ++j) bv2[j] = Bs[kk][tx + 16 * j];
#pragma unroll
      for (int a = 0; a < 4; ++a)
#pragma unroll
        for (int b = 0; b < 4; ++b)
          acc[a][b] += av2[a] * bv2[b];
    }
    __syncthreads();
  }
#pragma unroll
  for (int a = 0; a < 4; ++a) {
    const int c = cBase + ty + 16 * a;
#pragma unroll
    for (int b = 0; b < 4; ++b) {
      const int n = nBase + tx + 16 * b;
      out[c * NPOS + n] = x[c * NPOS + n] + bp[c] + acc[a][b];
    }
  }
}

// ---------------------------------------------------------------------------
// Permute wp: wpp[co][h*64+d] = wp[co][d*8+h]
// ---------------------------------------------------------------------------
__global__ __launch_bounds__(256) void permw_k(const float* __restrict__ wp,
                                               float* __restrict__ wpp) {
  const int i = blockIdx.x * 256 + threadIdx.x;  // 0..262143
  const int co = i >> 9;
  const int s = i & 511;
  const int hh = s >> 6;
  const int dd = s & 63;
  wpp[i] = wp[co * CH + dd * 8 + hh];
}

// ---------------------------------------------------------------------------
// Gather attention. One wave per (q_pos, head). Block = 4 waves.
// q_t/k_t/v_t are (NPOS, CH) with channel = h*64+d. o_t same layout.
// ---------------------------------------------------------------------------
__global__ __launch_bounds__(256) void attn_k(const float* __restrict__ q_t,
    const float* __restrict__ k_t, const float* __restrict__ v_t,
    const int* __restrict__ aidx, const int* __restrict__ vmask,
    float* __restrict__ o_t) {
  __shared__ float qs[4][64];
  __shared__ float wls[4][KATT];
  __shared__ int ils[4][KATT];
  const int w = threadIdx.x >> 6;
  const int lane = threadIdx.x & 63;
  const int p = blockIdx.x * 4 + w;  // p = q_pos*8 + head
  const int hd = p & 7;
  const int qpos = p >> 3;

  qs[w][lane] = q_t[qpos * CH + hd * 64 + lane];

  const int i0 = qpos * KATT + lane;
  const int idx0 = aidx[i0];
  const int idx1 = aidx[i0 + 64];
  const int m0 = vmask[i0];
  const int m1 = vmask[i0 + 64];
  __syncthreads();

  // QK^T: each lane handles keys (lane) and (lane+64)
  float s0 = 0.f, s1 = 0.f;
  {
    const float* k0p = k_t + idx0 * CH + hd * 64;
    const float* k1p = k_t + idx1 * CH + hd * 64;
#pragma unroll
    for (int d0 = 0; d0 < 64; d0 += 4) {
      const float4 a = *(const float4*)&k0p[d0];
      const float4 b = *(const float4*)&k1p[d0];
      const float q0 = qs[w][d0], q1 = qs[w][d0 + 1];
      const float q2 = qs[w][d0 + 2], q3 = qs[w][d0 + 3];
      s0 += a.x * q0 + a.y * q1 + a.z * q2 + a.w * q3;
      s1 += b.x * q0 + b.y * q1 + b.z * q2 + b.w * q3;
    }
  }
  if (!m0) s0 = -INFINITY;
  if (!m1) s1 = -INFINITY;

  // wave-wide softmax over the 128 scores
  float m = fmaxf(s0, s1);
#pragma unroll
  for (int off = 32; off > 0; off >>= 1) m = fmaxf(m, __shfl_xor(m, off));
  const float e0 = __expf(s0 - m);
  const float e1 = __expf(s1 - m);
  float sum = e0 + e1;
#pragma unroll
  for (int off = 32; off > 0; off >>= 1) sum += __shfl_xor(sum, off);
  const float inv = 1.f / sum;

  wls[w][lane] = e0 * inv;
  wls[w][lane + 64] = e1 * inv;
  ils[w][lane] = idx0;
  ils[w][lane + 64] = idx1;
  __syncthreads();

  // PV: lane = d
  float o = 0.f;
  for (int kk = 0; kk < KATT; ++kk) {
    const float wk = wls[w][kk];  // broadcast -> wave-uniform branch
    if (wk != 0.f) {
      const int ii = ils[w][kk];
      o += wk * v_t[ii * CH + hd * 64 + lane];
    }
  }
  o_t[qpos * CH + hd * 64 + lane] = o;
}

// ---------------------------------------------------------------------------
extern "C" void kernel_launch(void* const* d_in, const int* in_sizes, int n_in,
                              void* d_out, int out_size, void* d_ws, size_t ws_size,
                              hipStream_t stream) {
  const float* x    = (const float*)d_in[0];
  const int* vmask  = (const int*)d_in[1];
  const int* aidx   = (const int*)d_in[2];
  const float* gnw  = (const float*)d_in[3];
  const float* gnb  = (const float*)d_in[4];
  const float* wq   = (const float*)d_in[5];
  const float* bq   = (const float*)d_in[6];
  const float* wk   = (const float*)d_in[7];
  const float* bk   = (const float*)d_in[8];
  const float* wv   = (const float*)d_in[9];
  const float* bv   = (const float*)d_in[10];
  const float* wp   = (const float*)d_in[11];
  const float* bp   = (const float*)d_in[12];
  float* out = (float*)d_out;

  char* ws = (char*)d_ws;
  float* hbuf = (float*)(ws);                  // 4 MB  (CH x NPOS)
  float* qt   = (float*)(ws + (4u << 20));     // 4 MB  (NPOS x CH)
  float* kt   = (float*)(ws + (8u << 20));     // 4 MB
  float* vt   = (float*)(ws + (12u << 20));    // 4 MB
  float* ot   = (float*)(ws + (16u << 20));    // 4 MB
  float* wpp  = (float*)(ws + (20u << 20));    // 1 MB
  // requires ws_size >= 21 MB

  gnorm_k<<<32, 256, 0, stream>>>(x, gnw, gnb, hbuf);

  dim3 gt(NPOS / 64, CH / 64);  // (32, 8)
  gemm_t_k<<<gt, 256, 0, stream>>>(hbuf, wq, bq, qt);
  gemm_t_k<<<gt, 256, 0, stream>>>(hbuf, wk, bk, kt);
  gemm_t_k<<<gt, 256, 0, stream>>>(hbuf, wv, bv, vt);

  permw_k<<<(CH * CH) / 256, 256, 0, stream>>>(wp, wpp);

  attn_k<<<(NPOS * NHEAD) / 4, 256, 0, stream>>>(qt, kt, vt, aidx, vmask, ot);

  gemm_r_k<<<dim3(NPOS / 64, CH / 64), 256, 0, stream>>>(ot, wpp, bp, x, out);
}

// Round 4
// 273.046 us; speedup vs baseline: 1.4806x; 1.4806x over previous
//
#include <hip/hip_runtime.h>
#include <hip/hip_bf16.h>
#include <math.h>

#define NPOS 2048
#define CH   512
#define KATT 128
#define NHEAD 8

typedef __attribute__((ext_vector_type(8))) short short8;
typedef __attribute__((ext_vector_type(4))) float f32x4;

static __device__ __forceinline__ ushort f2bf(float f) {
  union { float f; unsigned u; } v; v.f = f;
  unsigned r = (v.u + 0x7FFFu + ((v.u >> 16) & 1u)) >> 16;
  return (ushort)r;
}

// ---------------------------------------------------------------------------
// GroupNorm -> transposed bf16 activation ht[pos][ch]  (NPOS x CH, bf16)
// One block per group (32 groups of 16 ch x 2048 pos).
// ---------------------------------------------------------------------------
__global__ __launch_bounds__(256) void gnorm_k(const float* __restrict__ x,
    const float* __restrict__ gw, const float* __restrict__ gb,
    ushort* __restrict__ ht) {
  const int g = blockIdx.x;
  const float* xp = x + g * 16 * NPOS;
  float s = 0.f, ss = 0.f;
  for (int i = threadIdx.x; i < 16 * NPOS; i += 256) {
    float v = xp[i];
    s += v;
    ss += v * v;
  }
  __shared__ float rs[256], rq[256];
  rs[threadIdx.x] = s;
  rq[threadIdx.x] = ss;
  __syncthreads();
  for (int off = 128; off > 0; off >>= 1) {
    if (threadIdx.x < (unsigned)off) {
      rs[threadIdx.x] += rs[threadIdx.x + off];
      rq[threadIdx.x] += rq[threadIdx.x + off];
    }
    __syncthreads();
  }
  const float inv_n = 1.f / (16.f * NPOS);
  const float mu = rs[0] * inv_n;
  const float var = rq[0] * inv_n - mu * mu;
  const float rstd = rsqrtf(var + 1e-6f);
  // y = x*(rstd*w) + (b - mu*rstd*w)
  float wc[16], bc[16];
#pragma unroll
  for (int c = 0; c < 16; ++c) {
    const float a = gw[g * 16 + c] * rstd;
    wc[c] = a;
    bc[c] = gb[g * 16 + c] - mu * a;
  }
  for (int pos = threadIdx.x; pos < NPOS; pos += 256) {
    unsigned pk[8];
#pragma unroll
    for (int c = 0; c < 8; ++c) {
      const unsigned lo = f2bf(xp[(2 * c) * NPOS + pos] * wc[2 * c] + bc[2 * c]);
      const unsigned hi = f2bf(xp[(2 * c + 1) * NPOS + pos] * wc[2 * c + 1] + bc[2 * c + 1]);
      pk[c] = lo | (hi << 16);
    }
    uint4* dst = (uint4*)(ht + pos * CH + g * 16);
    dst[0] = make_uint4(pk[0], pk[1], pk[2], pk[3]);
    dst[1] = make_uint4(pk[4], pk[5], pk[6], pk[7]);
  }
}

// ---------------------------------------------------------------------------
// Convert wq/wk/wv fp32 (512,512) -> bf16, same layout. grid (256, 3).
// ---------------------------------------------------------------------------
__global__ __launch_bounds__(256) void convw_k(const float* __restrict__ wq,
    const float* __restrict__ wk, const float* __restrict__ wv,
    ushort* __restrict__ oq, ushort* __restrict__ ok, ushort* __restrict__ ov) {
  const float* src = blockIdx.y == 0 ? wq : (blockIdx.y == 1 ? wk : wv);
  ushort* dst = blockIdx.y == 0 ? oq : (blockIdx.y == 1 ? ok : ov);
  const int i = (blockIdx.x * 256 + threadIdx.x) * 4;
  const float4 v = *(const float4*)(src + i);
  uint2 p;
  p.x = (unsigned)f2bf(v.x) | ((unsigned)f2bf(v.y) << 16);
  p.y = (unsigned)f2bf(v.z) | ((unsigned)f2bf(v.w) << 16);
  *(uint2*)(dst + i) = p;
}

// ---------------------------------------------------------------------------
// Permute+convert wp: wppb[co][h*64+d] = bf16(wp[co][d*8+h])
// ---------------------------------------------------------------------------
__global__ __launch_bounds__(256) void permw_k(const float* __restrict__ wp,
                                               ushort* __restrict__ wppb) {
  const int i = blockIdx.x * 256 + threadIdx.x;  // 0..262143
  const int co = i >> 9;
  const int sl = i & 511;
  const int hh = sl >> 6;
  const int dd = sl & 63;
  wppb[i] = f2bf(wp[co * CH + dd * 8 + hh]);
}

// ---------------------------------------------------------------------------
// bf16 MFMA GEMM:  out[m][n] = sum_k A[m][k]*B[n][k] + bias(+resid)
// A: M x 512 bf16 row-major. B: N x 512 bf16 row-major. out fp32, ld=ldout.
// grid = (M/64, N/64), 256 threads = 4 waves, each wave 32x32 (2x2 frags).
// LDS tiles [64 rows][64 k] bf16 with XOR swizzle byte^=((row&7)<<4) (T2/G4).
// ---------------------------------------------------------------------------
__global__ __launch_bounds__(256) void mm_k(const ushort* __restrict__ A,
    const ushort* __restrict__ Bm, const float* __restrict__ bias,
    const int bias_on_m, const float* __restrict__ resid,
    float* __restrict__ outF, const int ldout) {
  __shared__ ushort As[64 * 64];
  __shared__ ushort Bs[64 * 64];
  const int mBase = blockIdx.x * 64;
  const int nBase = blockIdx.y * 64;
  const int tid = threadIdx.x;
  const int l = tid & 63;
  const int w = tid >> 6;
  const int wm = w >> 1, wn = w & 1;
  f32x4 acc[2][2] = {};

  for (int k0 = 0; k0 < 512; k0 += 64) {
#pragma unroll
    for (int p = 0; p < 2; ++p) {
      const int flat = tid + p * 256;          // 16B units, 512 = 64 rows x 8
      const int row = flat >> 3;
      const int colB = (flat & 7) << 4;        // byte col within 128B row
      const int swz = colB ^ ((row & 7) << 4);
      const uint4 va = *(const uint4*)(A + (mBase + row) * 512 + k0 + (colB >> 1));
      *(uint4*)((char*)As + row * 128 + swz) = va;
      const uint4 vb = *(const uint4*)(Bm + (nBase + row) * 512 + k0 + (colB >> 1));
      *(uint4*)((char*)Bs + row * 128 + swz) = vb;
    }
    __syncthreads();
#pragma unroll
    for (int ks = 0; ks < 2; ++ks) {
      short8 af[2], bfr[2];
      const int kb = ks * 64 + ((l >> 4) << 4);  // byte offset of this lane's 8 bf16
#pragma unroll
      for (int f = 0; f < 2; ++f) {
        const int ra = wm * 32 + f * 16 + (l & 15);
        af[f] = *(const short8*)((const char*)As + ra * 128 + (kb ^ ((ra & 7) << 4)));
        const int rb = wn * 32 + f * 16 + (l & 15);
        bfr[f] = *(const short8*)((const char*)Bs + rb * 128 + (kb ^ ((rb & 7) << 4)));
      }
#pragma unroll
      for (int fm = 0; fm < 2; ++fm)
#pragma unroll
        for (int fn = 0; fn < 2; ++fn)
          acc[fm][fn] = __builtin_amdgcn_mfma_f32_16x16x32_bf16(af[fm], bfr[fn], acc[fm][fn], 0, 0, 0);
    }
    __syncthreads();
  }

  // epilogue: D row = 4*(l>>4)+r, col = l&15 (m89-verified layout)
#pragma unroll
  for (int fm = 0; fm < 2; ++fm) {
#pragma unroll
    for (int fn = 0; fn < 2; ++fn) {
      const int col = nBase + wn * 32 + fn * 16 + (l & 15);
#pragma unroll
      for (int r = 0; r < 4; ++r) {
        const int rowm = mBase + wm * 32 + fm * 16 + ((l >> 4) << 2) + r;
        float v = acc[fm][fn][r] + (bias_on_m ? bias[rowm] : bias[col]);
        const int off = rowm * ldout + col;
        if (resid) v += resid[off];
        outF[off] = v;
      }
    }
  }
}

// ---------------------------------------------------------------------------
// Gather attention. One wave per (q_pos, head). Block = 4 waves.
// q_t/k_t/v_t fp32 (NPOS, CH) with channel = h*64+d. Output ot bf16 (NPOS, CH).
// ---------------------------------------------------------------------------
__global__ __launch_bounds__(256) void attn_k(const float* __restrict__ q_t,
    const float* __restrict__ k_t, const float* __restrict__ v_t,
    const int* __restrict__ aidx, const int* __restrict__ vmask,
    ushort* __restrict__ ot) {
  __shared__ float qs[4][64];
  __shared__ float wls[4][KATT];
  __shared__ int ils[4][KATT];
  const int w = threadIdx.x >> 6;
  const int lane = threadIdx.x & 63;
  const int p = blockIdx.x * 4 + w;  // p = q_pos*8 + head
  const int hd = p & 7;
  const int qpos = p >> 3;

  qs[w][lane] = q_t[qpos * CH + hd * 64 + lane];

  const int i0 = qpos * KATT + lane;
  const int idx0 = aidx[i0];
  const int idx1 = aidx[i0 + 64];
  const int m0 = vmask[i0];
  const int m1 = vmask[i0 + 64];
  __syncthreads();

  // QK^T: each lane handles keys (lane) and (lane+64)
  float s0 = 0.f, s1 = 0.f;
  {
    const float* k0p = k_t + idx0 * CH + hd * 64;
    const float* k1p = k_t + idx1 * CH + hd * 64;
#pragma unroll
    for (int d0 = 0; d0 < 64; d0 += 4) {
      const float4 a = *(const float4*)&k0p[d0];
      const float4 b = *(const float4*)&k1p[d0];
      const float q0 = qs[w][d0], q1 = qs[w][d0 + 1];
      const float q2 = qs[w][d0 + 2], q3 = qs[w][d0 + 3];
      s0 += a.x * q0 + a.y * q1 + a.z * q2 + a.w * q3;
      s1 += b.x * q0 + b.y * q1 + b.z * q2 + b.w * q3;
    }
  }
  if (!m0) s0 = -INFINITY;
  if (!m1) s1 = -INFINITY;

  // wave-wide softmax over the 128 scores
  float m = fmaxf(s0, s1);
#pragma unroll
  for (int off = 32; off > 0; off >>= 1) m = fmaxf(m, __shfl_xor(m, off));
  const float e0 = __expf(s0 - m);
  const float e1 = __expf(s1 - m);
  float sum = e0 + e1;
#pragma unroll
  for (int off = 32; off > 0; off >>= 1) sum += __shfl_xor(sum, off);
  const float inv = 1.f / sum;

  wls[w][lane] = e0 * inv;
  wls[w][lane + 64] = e1 * inv;
  ils[w][lane] = idx0;
  ils[w][lane + 64] = idx1;
  __syncthreads();

  // PV: lane = d. Unconditional (masked weights are exactly 0), unrolled x8
  // so 8 gather loads are in flight per wave (latency-bound fix).
  const float* vb = v_t + hd * 64 + lane;
  float o = 0.f;
  for (int kk = 0; kk < KATT; kk += 8) {
    float wk[8], vv[8];
#pragma unroll
    for (int u = 0; u < 8; ++u) {
      wk[u] = wls[w][kk + u];
      vv[u] = vb[ils[w][kk + u] * CH];
    }
#pragma unroll
    for (int u = 0; u < 8; ++u) o += wk[u] * vv[u];
  }
  ot[qpos * CH + hd * 64 + lane] = f2bf(o);
}

// ---------------------------------------------------------------------------
extern "C" void kernel_launch(void* const* d_in, const int* in_sizes, int n_in,
                              void* d_out, int out_size, void* d_ws, size_t ws_size,
                              hipStream_t stream) {
  const float* x    = (const float*)d_in[0];
  const int* vmask  = (const int*)d_in[1];
  const int* aidx   = (const int*)d_in[2];
  const float* gnw  = (const float*)d_in[3];
  const float* gnb  = (const float*)d_in[4];
  const float* wq   = (const float*)d_in[5];
  const float* bq   = (const float*)d_in[6];
  const float* wk   = (const float*)d_in[7];
  const float* bk   = (const float*)d_in[8];
  const float* wv   = (const float*)d_in[9];
  const float* bv   = (const float*)d_in[10];
  const float* wp   = (const float*)d_in[11];
  const float* bp   = (const float*)d_in[12];
  float* out = (float*)d_out;

  char* ws = (char*)d_ws;
  ushort* ht   = (ushort*)(ws);                 // 2 MB  (NPOS x CH bf16)
  float*  qt   = (float*)(ws + (2u  << 20));    // 4 MB  (NPOS x CH f32)
  float*  kt   = (float*)(ws + (6u  << 20));    // 4 MB
  float*  vt   = (float*)(ws + (10u << 20));    // 4 MB
  ushort* ot   = (ushort*)(ws + (14u << 20));   // 2 MB  (NPOS x CH bf16)
  ushort* wqb  = (ushort*)(ws + (16u << 20));   // 0.5 MB
  ushort* wkb  = (ushort*)(ws + (16u << 20) + (512u << 10));
  ushort* wvb  = (ushort*)(ws + (17u << 20));
  ushort* wppb = (ushort*)(ws + (17u << 20) + (512u << 10));
  // total 18 MB

  gnorm_k<<<32, 256, 0, stream>>>(x, gnw, gnb, ht);
  convw_k<<<dim3(256, 3), 256, 0, stream>>>(wq, wk, wv, wqb, wkb, wvb);
  permw_k<<<(CH * CH) / 256, 256, 0, stream>>>(wp, wppb);

  // Q/K/V: M=NPOS (pos rows), N=CH, out fp32 (NPOS, CH), bias on n
  dim3 gqkv(NPOS / 64, CH / 64);  // (32, 8)
  mm_k<<<gqkv, 256, 0, stream>>>(ht, wqb, bq, 0, nullptr, qt, CH);
  mm_k<<<gqkv, 256, 0, stream>>>(ht, wkb, bk, 0, nullptr, kt, CH);
  mm_k<<<gqkv, 256, 0, stream>>>(ht, wvb, bv, 0, nullptr, vt, CH);

  attn_k<<<(NPOS * NHEAD) / 4, 256, 0, stream>>>(qt, kt, vt, aidx, vmask, ot);

  // proj: M=CH (c rows), N=NPOS, out fp32 (CH, NPOS), bias on m, residual x
  dim3 gp(CH / 64, NPOS / 64);  // (8, 32)
  mm_k<<<gp, 256, 0, stream>>>(wppb, ot, bp, 1, x, out, NPOS);
}

// Round 6
// 194.896 us; speedup vs baseline: 2.0743x; 1.4010x over previous
//
#include <hip/hip_runtime.h>
#include <hip/hip_bf16.h>
#include <math.h>

#define NPOS 2048
#define CH   512
#define KATT 128
#define NHEAD 8

typedef __attribute__((ext_vector_type(8))) short short8;
typedef __attribute__((ext_vector_type(4))) float f32x4;

static __device__ __forceinline__ ushort f2bf(float f) {
  union { float f; unsigned u; } v; v.f = f;
  unsigned r = (v.u + 0x7FFFu + ((v.u >> 16) & 1u)) >> 16;
  return (ushort)r;
}

// ---------------------------------------------------------------------------
// GroupNorm -> transposed bf16 activation ht[pos][ch]  (NPOS x CH, bf16)
// ---------------------------------------------------------------------------
__global__ __launch_bounds__(256) void gnorm_k(const float* __restrict__ x,
    const float* __restrict__ gw, const float* __restrict__ gb,
    ushort* __restrict__ ht) {
  const int g = blockIdx.x;
  const float* xp = x + g * 16 * NPOS;
  float s = 0.f, ss = 0.f;
  for (int i = threadIdx.x; i < 16 * NPOS; i += 256) {
    float v = xp[i];
    s += v;
    ss += v * v;
  }
  __shared__ float rs[256], rq[256];
  rs[threadIdx.x] = s;
  rq[threadIdx.x] = ss;
  __syncthreads();
  for (int off = 128; off > 0; off >>= 1) {
    if (threadIdx.x < (unsigned)off) {
      rs[threadIdx.x] += rs[threadIdx.x + off];
      rq[threadIdx.x] += rq[threadIdx.x + off];
    }
    __syncthreads();
  }
  const float inv_n = 1.f / (16.f * NPOS);
  const float mu = rs[0] * inv_n;
  const float var = rq[0] * inv_n - mu * mu;
  const float rstd = rsqrtf(var + 1e-6f);
  float wc[16], bc[16];
#pragma unroll
  for (int c = 0; c < 16; ++c) {
    const float a = gw[g * 16 + c] * rstd;
    wc[c] = a;
    bc[c] = gb[g * 16 + c] - mu * a;
  }
  for (int pos = threadIdx.x; pos < NPOS; pos += 256) {
    unsigned pk[8];
#pragma unroll
    for (int c = 0; c < 8; ++c) {
      const unsigned lo = f2bf(xp[(2 * c) * NPOS + pos] * wc[2 * c] + bc[2 * c]);
      const unsigned hi = f2bf(xp[(2 * c + 1) * NPOS + pos] * wc[2 * c + 1] + bc[2 * c + 1]);
      pk[c] = lo | (hi << 16);
    }
    uint4* dst = (uint4*)(ht + pos * CH + g * 16);
    dst[0] = make_uint4(pk[0], pk[1], pk[2], pk[3]);
    dst[1] = make_uint4(pk[4], pk[5], pk[6], pk[7]);
  }
}

// ---------------------------------------------------------------------------
// Convert wq/wk/wv fp32 (512,512) -> bf16 into contiguous wqkv buffer.
// ---------------------------------------------------------------------------
__global__ __launch_bounds__(256) void convw_k(const float* __restrict__ wq,
    const float* __restrict__ wk, const float* __restrict__ wv,
    ushort* __restrict__ oq, ushort* __restrict__ ok, ushort* __restrict__ ov) {
  const float* src = blockIdx.y == 0 ? wq : (blockIdx.y == 1 ? wk : wv);
  ushort* dst = blockIdx.y == 0 ? oq : (blockIdx.y == 1 ? ok : ov);
  const int i = (blockIdx.x * 256 + threadIdx.x) * 4;
  const float4 v = *(const float4*)(src + i);
  uint2 p;
  p.x = (unsigned)f2bf(v.x) | ((unsigned)f2bf(v.y) << 16);
  p.y = (unsigned)f2bf(v.z) | ((unsigned)f2bf(v.w) << 16);
  *(uint2*)(dst + i) = p;
}

// ---------------------------------------------------------------------------
// Permute+convert wp: wppb[co][h*64+d] = bf16(wp[co][d*8+h])
// ---------------------------------------------------------------------------
__global__ __launch_bounds__(256) void permw_k(const float* __restrict__ wp,
                                               ushort* __restrict__ wppb) {
  const int i = blockIdx.x * 256 + threadIdx.x;
  const int co = i >> 9;
  const int sl = i & 511;
  const int hh = sl >> 6;
  const int dd = sl & 63;
  wppb[i] = f2bf(wp[co * CH + dd * 8 + hh]);
}

// ---------------------------------------------------------------------------
// Concat bq|bk|bv -> bqkv (1536 floats)
// ---------------------------------------------------------------------------
__global__ __launch_bounds__(256) void packb_k(const float* __restrict__ bq,
    const float* __restrict__ bk, const float* __restrict__ bv,
    float* __restrict__ bqkv) {
  const int i = blockIdx.x * 256 + threadIdx.x;  // 0..1535
  bqkv[i] = i < 512 ? bq[i] : (i < 1024 ? bk[i - 512] : bv[i - 1024]);
}

// ---------------------------------------------------------------------------
// bf16 MFMA GEMM, tile 32(M) x 64(N), K=512. 256 threads = 4 waves,
// wave (wm,wn): wm=w>>1 covers 16 rows, wn=w&1 covers 32 cols (2 frags).
// MODE 0: fused QKV   -> out buf (col>>9), offset rowm*CH + (col&511), bias[col]
// MODE 1: proj+resid  -> out rowm*NPOS + col, bias[rowm], + resid
// ---------------------------------------------------------------------------
template<int MODE>
__global__ __launch_bounds__(256) void mm_k(const ushort* __restrict__ A,
    const ushort* __restrict__ Bm, const float* __restrict__ bias,
    const float* __restrict__ resid, float* __restrict__ outF) {
  __shared__ ushort As[32 * 64];
  __shared__ ushort Bs[64 * 64];
  const int mBase = blockIdx.x * 32;
  const int nBase = blockIdx.y * 64;
  const int tid = threadIdx.x;
  const int l = tid & 63;
  const int w = tid >> 6;
  const int wm = w >> 1, wn = w & 1;
  f32x4 acc[2] = {};

  const int rowA = tid >> 3;
  const int colBy = (tid & 7) << 4;
  const int swzA = colBy ^ ((rowA & 7) << 4);

  for (int k0 = 0; k0 < 512; k0 += 64) {
    {
      const uint4 va = *(const uint4*)(A + (mBase + rowA) * 512 + k0 + (colBy >> 1));
      *(uint4*)((char*)As + rowA * 128 + swzA) = va;
#pragma unroll
      for (int p = 0; p < 2; ++p) {
        const int flat = tid + p * 256;
        const int row = flat >> 3;
        const int cB = (flat & 7) << 4;
        const uint4 vb = *(const uint4*)(Bm + (nBase + row) * 512 + k0 + (cB >> 1));
        *(uint4*)((char*)Bs + row * 128 + (cB ^ ((row & 7) << 4))) = vb;
      }
    }
    __syncthreads();
#pragma unroll
    for (int ks = 0; ks < 2; ++ks) {
      const int kb = ks * 64 + ((l >> 4) << 4);
      const int ra = wm * 16 + (l & 15);
      const short8 af = *(const short8*)((const char*)As + ra * 128 + (kb ^ ((ra & 7) << 4)));
      short8 bfr[2];
#pragma unroll
      for (int fn = 0; fn < 2; ++fn) {
        const int rb = wn * 32 + fn * 16 + (l & 15);
        bfr[fn] = *(const short8*)((const char*)Bs + rb * 128 + (kb ^ ((rb & 7) << 4)));
      }
#pragma unroll
      for (int fn = 0; fn < 2; ++fn)
        acc[fn] = __builtin_amdgcn_mfma_f32_16x16x32_bf16(af, bfr[fn], acc[fn], 0, 0, 0);
    }
    __syncthreads();
  }

#pragma unroll
  for (int fn = 0; fn < 2; ++fn) {
    const int col = nBase + wn * 32 + fn * 16 + (l & 15);
#pragma unroll
    for (int r = 0; r < 4; ++r) {
      const int rowm = mBase + wm * 16 + ((l >> 4) << 2) + r;
      if (MODE == 0) {
        const int off = (col >> 9) * (NPOS * CH) + rowm * CH + (col & 511);
        outF[off] = acc[fn][r] + bias[col];
      } else {
        const int off = rowm * NPOS + col;
        outF[off] = acc[fn][r] + bias[rowm] + resid[off];
      }
    }
  }
}

// ---------------------------------------------------------------------------
// Gather attention, quad-cooperative QK. One wave per (qpos, head).
// QK: quad (4 lanes) owns one key; lane sub reads 16B chunks -> each vmem
// instruction covers 16 rows x 64 contiguous bytes (full cache lines).
// ---------------------------------------------------------------------------
__global__ __launch_bounds__(256) void attn_k(const float* __restrict__ qt,
    const float* __restrict__ kt, const float* __restrict__ vt,
    const int* __restrict__ aidx, const int* __restrict__ vmask,
    ushort* __restrict__ ot) {
  __shared__ float wls[4][KATT];
  __shared__ int ils[4][KATT];
  const int w = threadIdx.x >> 6;
  const int lane = threadIdx.x & 63;
  const int p = blockIdx.x * 4 + w;  // p = qpos*8 + head
  const int hd = p & 7;
  const int qpos = p >> 3;
  const int quad = lane >> 2;  // 0..15: key slot within pass
  const int sub = lane & 3;    // 0..3: 16B chunk within 64B segment

  // q in registers: floats t*16 + sub*4 .. +3 for t=0..3
  const float* qb = qt + qpos * CH + hd * 64;
  float4 qv[4];
#pragma unroll
  for (int t = 0; t < 4; ++t) qv[t] = *(const float4*)(qb + t * 16 + sub * 4);

  const int* arow = aidx + qpos * KATT;
  const int* mrow = vmask + qpos * KATT;
  int idx8[8], m8[8];
#pragma unroll
  for (int kp = 0; kp < 8; ++kp) {
    idx8[kp] = arow[kp * 16 + quad];
    m8[kp] = mrow[kp * 16 + quad];
  }

  float sc[8];
#pragma unroll
  for (int kp = 0; kp < 8; ++kp) {
    const float* kr = kt + idx8[kp] * CH + hd * 64;
    float s = 0.f;
#pragma unroll
    for (int t = 0; t < 4; ++t) {
      const float4 kc = *(const float4*)(kr + t * 16 + sub * 4);
      s += kc.x * qv[t].x + kc.y * qv[t].y + kc.z * qv[t].z + kc.w * qv[t].w;
    }
    s += __shfl_xor(s, 1);
    s += __shfl_xor(s, 2);
    sc[kp] = m8[kp] ? s : -INFINITY;
  }

  // softmax across 128 keys (each key replicated over the 4 sub-lanes)
  float mx = sc[0];
#pragma unroll
  for (int kp = 1; kp < 8; ++kp) mx = fmaxf(mx, sc[kp]);
#pragma unroll
  for (int off = 4; off < 64; off <<= 1) mx = fmaxf(mx, __shfl_xor(mx, off));

  float e[8], lsum = 0.f;
#pragma unroll
  for (int kp = 0; kp < 8; ++kp) {
    e[kp] = __expf(sc[kp] - mx);
    lsum += e[kp];
  }
#pragma unroll
  for (int off = 4; off < 64; off <<= 1) lsum += __shfl_xor(lsum, off);
  const float inv = 1.f / lsum;

  if (sub == 0) {
#pragma unroll
    for (int kp = 0; kp < 8; ++kp) {
      wls[w][kp * 16 + quad] = e[kp] * inv;
      ils[w][kp * 16 + quad] = idx8[kp];
    }
  }
  __syncthreads();

  // PV: lane = d, coalesced 256B V-row reads, 8 gathers in flight
  const float* vb = vt + hd * 64 + lane;
  float o = 0.f;
  for (int kk = 0; kk < KATT; kk += 8) {
    float wk[8], vv[8];
#pragma unroll
    for (int u = 0; u < 8; ++u) {
      wk[u] = wls[w][kk + u];
      vv[u] = vb[ils[w][kk + u] * CH];
    }
#pragma unroll
    for (int u = 0; u < 8; ++u) o += wk[u] * vv[u];
  }
  ot[qpos * CH + hd * 64 + lane] = f2bf(o);
}

// ---------------------------------------------------------------------------
extern "C" void kernel_launch(void* const* d_in, const int* in_sizes, int n_in,
                              void* d_out, int out_size, void* d_ws, size_t ws_size,
                              hipStream_t stream) {
  const float* x    = (const float*)d_in[0];
  const int* vmask  = (const int*)d_in[1];
  const int* aidx   = (const int*)d_in[2];
  const float* gnw  = (const float*)d_in[3];
  const float* gnb  = (const float*)d_in[4];
  const float* wq   = (const float*)d_in[5];
  const float* bq   = (const float*)d_in[6];
  const float* wk   = (const float*)d_in[7];
  const float* bk   = (const float*)d_in[8];
  const float* wv   = (const float*)d_in[9];
  const float* bv   = (const float*)d_in[10];
  const float* wp   = (const float*)d_in[11];
  const float* bp   = (const float*)d_in[12];
  float* out = (float*)d_out;

  char* ws = (char*)d_ws;
  ushort* ht    = (ushort*)(ws);                          // 2 MB (NPOS x CH bf16)
  float*  qt    = (float*)(ws + (2u  << 20));             // 4 MB (NPOS x CH f32)
  float*  kt    = (float*)(ws + (6u  << 20));             // 4 MB (contiguous after qt)
  float*  vt    = (float*)(ws + (10u << 20));             // 4 MB (contiguous after kt)
  ushort* ot    = (ushort*)(ws + (14u << 20));            // 2 MB (NPOS x CH bf16)
  ushort* wqb   = (ushort*)(ws + (16u << 20));            // 0.5 MB  } contiguous
  ushort* wkb   = (ushort*)(ws + (16u << 20) + (512u << 10));  //   } (1536,512) bf16
  ushort* wvb   = (ushort*)(ws + (17u << 20));            //        }
  ushort* wppb  = (ushort*)(ws + (17u << 20) + (512u << 10));  // 0.5 MB
  float*  bqkv  = (float*)(ws + (18u << 20));             // 6 KB
  // total ~18 MB (ws_size was >= 21 MB in prior rounds)

  gnorm_k<<<32, 256, 0, stream>>>(x, gnw, gnb, ht);
  convw_k<<<dim3(256, 3), 256, 0, stream>>>(wq, wk, wv, wqb, wkb, wvb);
  permw_k<<<(CH * CH) / 256, 256, 0, stream>>>(wp, wppb);
  packb_k<<<6, 256, 0, stream>>>(bq, bk, bv, bqkv);

  // fused QKV: A=ht (2048x512), B=wqkv (1536x512), grid 64x24 = 1536 blocks
  mm_k<0><<<dim3(NPOS / 32, 1536 / 64), 256, 0, stream>>>(ht, wqb, bqkv, nullptr, qt);

  attn_k<<<(NPOS * NHEAD) / 4, 256, 0, stream>>>(qt, kt, vt, aidx, vmask, ot);

  // proj: A=wppb (512x512), B=ot (2048x512), grid 16x32 = 512 blocks
  mm_k<1><<<dim3(CH / 32, NPOS / 64), 256, 0, stream>>>(wppb, ot, bp, x, out);
}

// Round 10
// 133.128 us; speedup vs baseline: 3.0367x; 1.4640x over previous
//
#include <hip/hip_runtime.h>
#include <hip/hip_bf16.h>
#include <math.h>

#define NPOS 2048
#define CH   512
#define KATT 128
#define NHEAD 8

typedef __attribute__((ext_vector_type(8))) short short8;
typedef __attribute__((ext_vector_type(4))) float f32x4;

static __device__ __forceinline__ ushort f2bf(float f) {
  union { float f; unsigned u; } v; v.f = f;
  unsigned r = (v.u + 0x7FFFu + ((v.u >> 16) & 1u)) >> 16;
  return (ushort)r;
}

// global -> LDS direct DMA, 16B per lane. LDS dest = base + lane*16 (linear).
static __device__ __forceinline__ void gl16(const void* g, void* l) {
  __builtin_amdgcn_global_load_lds(
      (const __attribute__((address_space(1))) unsigned int*)(uintptr_t)g,
      (__attribute__((address_space(3))) unsigned int*)(uintptr_t)l, 16, 0, 0);
}

// ---------------------------------------------------------------------------
// GroupNorm stats pass 1: 256 blocks = 32 groups x 8 octants.
// part[b] = (sum, sumsq) of octant.
// ---------------------------------------------------------------------------
__global__ __launch_bounds__(256) void gn1_k(const float* __restrict__ x,
                                             float* __restrict__ part) {
  const int b = blockIdx.x;
  const float* xp = x + (b >> 3) * 32768 + (b & 7) * 4096;
  float s = 0.f, ss = 0.f;
  for (int i = threadIdx.x; i < 4096; i += 256) {
    float v = xp[i];
    s += v;
    ss += v * v;
  }
  __shared__ float rs[256], rq[256];
  rs[threadIdx.x] = s;
  rq[threadIdx.x] = ss;
  __syncthreads();
  for (int off = 128; off > 0; off >>= 1) {
    if (threadIdx.x < (unsigned)off) {
      rs[threadIdx.x] += rs[threadIdx.x + off];
      rq[threadIdx.x] += rq[threadIdx.x + off];
    }
    __syncthreads();
  }
  if (threadIdx.x == 0) {
    part[b * 2] = rs[0];
    part[b * 2 + 1] = rq[0];
  }
}

// ---------------------------------------------------------------------------
// GroupNorm pass 2 + bf16 transpose: 512 blocks = 32 groups x 16 pos-chunks.
// ht[pos][ch] bf16.
// ---------------------------------------------------------------------------
__global__ __launch_bounds__(256) void gn2_k(const float* __restrict__ x,
    const float* __restrict__ part, const float* __restrict__ gw,
    const float* __restrict__ gb, ushort* __restrict__ ht) {
  const int g = blockIdx.x >> 4;
  const int chunk = blockIdx.x & 15;
  float s = 0.f, ss = 0.f;
#pragma unroll
  for (int o = 0; o < 8; ++o) {
    s += part[(g * 8 + o) * 2];
    ss += part[(g * 8 + o) * 2 + 1];
  }
  const float inv_n = 1.f / 32768.f;
  const float mu = s * inv_n;
  const float var = ss * inv_n - mu * mu;
  const float rstd = rsqrtf(var + 1e-6f);

  const int half = threadIdx.x >> 7;            // 0/1 -> 8 channels
  const int pos = chunk * 128 + (threadIdx.x & 127);
  unsigned pk[4];
#pragma unroll
  for (int c2 = 0; c2 < 4; ++c2) {
    unsigned p = 0;
#pragma unroll
    for (int e = 0; e < 2; ++e) {
      const int cc = half * 8 + c2 * 2 + e;
      const int ch = g * 16 + cc;
      const float a = gw[ch] * rstd;
      const float v = x[ch * NPOS + pos] * a + (gb[ch] - mu * a);
      p |= ((unsigned)f2bf(v)) << (16 * e);
    }
    pk[c2] = p;
  }
  *(uint4*)(ht + pos * CH + g * 16 + half * 8) = make_uint4(pk[0], pk[1], pk[2], pk[3]);
}

// ---------------------------------------------------------------------------
// Fused prep: 897 blocks.
//  bid<768  : convert wq|wk|wv fp32 -> bf16 (contiguous wqkv)
//  768..895 : permute+convert wp -> wppb[co][h*64+d] (LDS-coalesced)
//  896      : pack biases
// ---------------------------------------------------------------------------
__global__ __launch_bounds__(256) void prep_k(const float* __restrict__ wq,
    const float* __restrict__ wk, const float* __restrict__ wv,
    const float* __restrict__ wp, const float* __restrict__ bq,
    const float* __restrict__ bk, const float* __restrict__ bv,
    ushort* __restrict__ wqkv, ushort* __restrict__ wppb,
    float* __restrict__ bqkv) {
  const int bid = blockIdx.x;
  if (bid < 768) {
    const int m = bid >> 8;
    const float* src = m == 0 ? wq : (m == 1 ? wk : wv);
    const int i = (bid & 255) * 1024 + threadIdx.x * 4;
    const float4 v = *(const float4*)(src + i);
    uint2 p;
    p.x = (unsigned)f2bf(v.x) | ((unsigned)f2bf(v.y) << 16);
    p.y = (unsigned)f2bf(v.z) | ((unsigned)f2bf(v.w) << 16);
    *(uint2*)(wqkv + m * 262144 + i) = p;
  } else if (bid < 896) {
    __shared__ float lds[2048];
    const int co0 = (bid - 768) * 4;
    for (int t = threadIdx.x; t < 2048; t += 256) lds[t] = wp[co0 * 512 + t];
    __syncthreads();
    ushort o8[8];
#pragma unroll
    for (int e = 0; e < 8; ++e) {
      const int jj = threadIdx.x * 8 + e;
      const int col = jj >> 9;
      const int sl = jj & 511;
      o8[e] = f2bf(lds[col * 512 + (sl & 63) * 8 + (sl >> 6)]);
    }
    *(uint4*)(wppb + co0 * 512 + threadIdx.x * 8) = *(uint4*)o8;
  } else {
    for (int i = threadIdx.x; i < 1536; i += 256)
      bqkv[i] = i < 512 ? bq[i] : (i < 1024 ? bk[i - 512] : bv[i - 1024]);
  }
}

// ---------------------------------------------------------------------------
// bf16 MFMA GEMM with global_load_lds staging (linear LDS dest,
// swizzle applied to SOURCE address; ds_read applies same XOR -> cancels).
// TM x 64 tile, K=512, BK=64, 4 waves (WM x WN grid), frag FM x FN.
// MODE 0: fused QKV out (col>>9 selects q/k/v buf). MODE 1: proj + residual.
// ---------------------------------------------------------------------------
template<int TM, int WN, int MODE>
__global__ __launch_bounds__(256) void mm_k(const ushort* __restrict__ A,
    const ushort* __restrict__ Bm, const float* __restrict__ bias,
    const float* __restrict__ resid, float* __restrict__ outF) {
  constexpr int WM = 4 / WN;
  constexpr int FM = TM / (WM * 16);
  constexpr int FN = 64 / (WN * 16);
  __shared__ ushort As[TM * 64];
  __shared__ ushort Bs[64 * 64];
  const int mBase = blockIdx.x * TM;
  const int nBase = blockIdx.y * 64;
  const int tid = threadIdx.x;
  const int l = tid & 63;
  const int w = tid >> 6;
  const int wm = w / WN, wn = w % WN;
  const int sub8 = l >> 3;        // row within 8-row DMA call
  const int c16 = (l & 7) << 4;   // byte col within 128B row
  f32x4 acc[FM][FN] = {};

  for (int k0 = 0; k0 < 512; k0 += 64) {
#pragma unroll
    for (int c = 0; c < TM / 32; ++c) {
      const int r0 = w * (TM / 4) + c * 8;
      const int row = r0 + sub8;
      const int sc = c16 ^ ((row & 7) << 4);
      gl16(A + (mBase + row) * 512 + k0 + (sc >> 1), (char*)As + r0 * 128);
    }
#pragma unroll
    for (int c = 0; c < 2; ++c) {
      const int r0 = w * 16 + c * 8;
      const int row = r0 + sub8;
      const int sc = c16 ^ ((row & 7) << 4);
      gl16(Bm + (nBase + row) * 512 + k0 + (sc >> 1), (char*)Bs + r0 * 128);
    }
    __syncthreads();
#pragma unroll
    for (int ks = 0; ks < 2; ++ks) {
      const int kb = ks * 64 + ((l >> 4) << 4);
      short8 afr[FM], bfr[FN];
#pragma unroll
      for (int fm = 0; fm < FM; ++fm) {
        const int ra = wm * (FM * 16) + fm * 16 + (l & 15);
        afr[fm] = *(const short8*)((const char*)As + ra * 128 + (kb ^ ((ra & 7) << 4)));
      }
#pragma unroll
      for (int fn = 0; fn < FN; ++fn) {
        const int rb = wn * (FN * 16) + fn * 16 + (l & 15);
        bfr[fn] = *(const short8*)((const char*)Bs + rb * 128 + (kb ^ ((rb & 7) << 4)));
      }
#pragma unroll
      for (int fm = 0; fm < FM; ++fm)
#pragma unroll
        for (int fn = 0; fn < FN; ++fn)
          acc[fm][fn] = __builtin_amdgcn_mfma_f32_16x16x32_bf16(afr[fm], bfr[fn], acc[fm][fn], 0, 0, 0);
    }
    __syncthreads();
  }

#pragma unroll
  for (int fm = 0; fm < FM; ++fm)
#pragma unroll
    for (int fn = 0; fn < FN; ++fn) {
      const int col = nBase + wn * (FN * 16) + fn * 16 + (l & 15);
#pragma unroll
      for (int r = 0; r < 4; ++r) {
        const int rowm = mBase + wm * (FM * 16) + fm * 16 + ((l >> 4) << 2) + r;
        if (MODE == 0) {
          const int off = (col >> 9) * (NPOS * CH) + rowm * CH + (col & 511);
          outF[off] = acc[fm][fn][r] + bias[col];
        } else {
          const int off = rowm * NPOS + col;
          outF[off] = acc[fm][fn][r] + bias[rowm] + resid[off];
        }
      }
    }
}

// ---------------------------------------------------------------------------
// Gather attention with valid-key compaction. One wave per (qpos, head),
// 4 independent waves/block, NO barriers (all LDS is per-wave).
// ---------------------------------------------------------------------------
__global__ __launch_bounds__(256) void attn_k(const float* __restrict__ qt,
    const float* __restrict__ kt, const float* __restrict__ vt,
    const int* __restrict__ aidx, const int* __restrict__ vmask,
    ushort* __restrict__ ot) {
  __shared__ int ils[4][KATT];
  __shared__ float scs[4][KATT];
  __shared__ float prs[4][2 * KATT];
  const int w = threadIdx.x >> 6;
  const int lane = threadIdx.x & 63;
  const int p = blockIdx.x * 4 + w;  // p = qpos*8 + head
  const int hd = p & 7;
  const int qpos = p >> 3;
  const int quad = lane >> 2;
  const int sub = lane & 3;
  int* ils_w = ils[w];
  float* scs_w = scs[w];
  float* prs_w = prs[w];

  // q chunks for quad-cooperative dot (sub owns 16B pieces)
  const float* qb = qt + qpos * CH + hd * 64;
  float4 qv[4];
#pragma unroll
  for (int t = 0; t < 4; ++t) qv[t] = *(const float4*)(qb + t * 16 + sub * 4);

  const int i0 = qpos * KATT + lane;
  const int idx0 = aidx[i0];
  const int idx1 = aidx[i0 + 64];
  const int m0 = vmask[i0];
  const int m1 = vmask[i0 + 64];

  // compact valid keys -> ils_w[0..nv)
  const unsigned long long b0 = __ballot(m0 != 0);
  const unsigned long long b1 = __ballot(m1 != 0);
  const int nv0 = __popcll(b0);
  const int nv = nv0 + __popcll(b1);
  const unsigned long long low = (1ull << lane) - 1ull;
  ils_w[lane] = 0;
  ils_w[lane + 64] = 0;
  if (m0) ils_w[__popcll(b0 & low)] = idx0;
  if (m1) ils_w[nv0 + __popcll(b1 & low)] = idx1;

  // QK over valid keys only: quad owns one key per pass
  for (int p8 = 0; p8 * 16 < nv; ++p8) {
    const int t = p8 * 16 + quad;          // < 128 always
    const int ki = ils_w[t];               // 0 for invalid slots (safe)
    const float* kr = kt + ki * CH + hd * 64;
    float s = 0.f;
#pragma unroll
    for (int tt = 0; tt < 4; ++tt) {
      const float4 kc = *(const float4*)(kr + tt * 16 + sub * 4);
      s += kc.x * qv[tt].x + kc.y * qv[tt].y + kc.z * qv[tt].z + kc.w * qv[tt].w;
    }
    s += __shfl_xor(s, 1);
    s += __shfl_xor(s, 2);
    if (sub == 0 && t < nv) scs_w[t] = s;
  }

  // softmax over the nv compacted scores
  float s0 = (lane < nv) ? scs_w[lane] : -INFINITY;
  float s1 = (lane + 64 < nv) ? scs_w[lane + 64] : -INFINITY;
  float mx = fmaxf(s0, s1);
#pragma unroll
  for (int off = 32; off > 0; off >>= 1) mx = fmaxf(mx, __shfl_xor(mx, off));
  const float e0 = __expf(s0 - mx);
  const float e1 = __expf(s1 - mx);
  float lsum = (lane < nv ? e0 : 0.f) + (lane + 64 < nv ? e1 : 0.f);
#pragma unroll
  for (int off = 32; off > 0; off >>= 1) lsum += __shfl_xor(lsum, off);
  const float inv = 1.f / lsum;

  if (lane < nv) {
    prs_w[2 * lane] = e0 * inv;
    prs_w[2 * lane + 1] = __int_as_float(ils_w[lane]);
  }
  if (lane + 64 < nv) {
    prs_w[2 * (lane + 64)] = e1 * inv;
    prs_w[2 * (lane + 64) + 1] = __int_as_float(ils_w[lane + 64]);
  }

  // PV over valid keys; lane = d; pairs read as uniform float4 (w,idx,w,idx)
  const float* vb = vt + hd * 64 + lane;
  float o = 0.f;
  int kk = 0;
  for (; kk + 8 <= nv; kk += 8) {
    const float4 c0 = *(const float4*)&prs_w[2 * kk];
    const float4 c1 = *(const float4*)&prs_w[2 * kk + 4];
    const float4 c2 = *(const float4*)&prs_w[2 * kk + 8];
    const float4 c3 = *(const float4*)&prs_w[2 * kk + 12];
    float vv[8];
    vv[0] = vb[__float_as_int(c0.y) * CH];
    vv[1] = vb[__float_as_int(c0.w) * CH];
    vv[2] = vb[__float_as_int(c1.y) * CH];
    vv[3] = vb[__float_as_int(c1.w) * CH];
    vv[4] = vb[__float_as_int(c2.y) * CH];
    vv[5] = vb[__float_as_int(c2.w) * CH];
    vv[6] = vb[__float_as_int(c3.y) * CH];
    vv[7] = vb[__float_as_int(c3.w) * CH];
    o += c0.x * vv[0] + c0.z * vv[1] + c1.x * vv[2] + c1.z * vv[3] +
         c2.x * vv[4] + c2.z * vv[5] + c3.x * vv[6] + c3.z * vv[7];
  }
  for (; kk < nv; ++kk) {
    const float2 c = *(const float2*)&prs_w[2 * kk];
    o += c.x * vb[__float_as_int(c.y) * CH];
  }
  ot[qpos * CH + hd * 64 + lane] = f2bf(o);
}

// ---------------------------------------------------------------------------
extern "C" void kernel_launch(void* const* d_in, const int* in_sizes, int n_in,
                              void* d_out, int out_size, void* d_ws, size_t ws_size,
                              hipStream_t stream) {
  const float* x    = (const float*)d_in[0];
  const int* vmask  = (const int*)d_in[1];
  const int* aidx   = (const int*)d_in[2];
  const float* gnw  = (const float*)d_in[3];
  const float* gnb  = (const float*)d_in[4];
  const float* wq   = (const float*)d_in[5];
  const float* bq   = (const float*)d_in[6];
  const float* wk   = (const float*)d_in[7];
  const float* bk   = (const float*)d_in[8];
  const float* wv   = (const float*)d_in[9];
  const float* bv   = (const float*)d_in[10];
  const float* wp   = (const float*)d_in[11];
  const float* bp   = (const float*)d_in[12];
  float* out = (float*)d_out;

  char* ws = (char*)d_ws;
  ushort* ht    = (ushort*)(ws);                          // 2 MB (NPOS x CH bf16)
  float*  qt    = (float*)(ws + (2u  << 20));             // 4 MB (NPOS x CH f32)
  float*  kt    = (float*)(ws + (6u  << 20));             // 4 MB
  float*  vt    = (float*)(ws + (10u << 20));             // 4 MB
  ushort* ot    = (ushort*)(ws + (14u << 20));            // 2 MB (NPOS x CH bf16)
  ushort* wqkv  = (ushort*)(ws + (16u << 20));            // 1.5 MB (1536 x 512 bf16)
  ushort* wppb  = (ushort*)(ws + (17u << 20) + (512u << 10));  // 0.5 MB
  float*  bqkv  = (float*)(ws + (18u << 20));             // 6 KB
  float*  part  = (float*)(ws + (18u << 20) + (32u << 10));    // 2 KB
  // total ~18.1 MB

  gn1_k<<<256, 256, 0, stream>>>(x, part);
  gn2_k<<<512, 256, 0, stream>>>(x, part, gnw, gnb, ht);
  prep_k<<<897, 256, 0, stream>>>(wq, wk, wv, wp, bq, bk, bv, wqkv, wppb, bqkv);

  // fused QKV: A=ht (2048x512), B=wqkv (1536x512) -> 768 blocks
  mm_k<64, 2, 0><<<dim3(NPOS / 64, 1536 / 64), 256, 0, stream>>>(ht, wqkv, bqkv, nullptr, qt);

  attn_k<<<(NPOS * NHEAD) / 4, 256, 0, stream>>>(qt, kt, vt, aidx, vmask, ot);

  // proj: A=wppb (512x512), B=ot (2048x512) -> 512 blocks
  mm_k<32, 4, 1><<<dim3(CH / 32, NPOS / 64), 256, 0, stream>>>(wppb, ot, bp, x, out);
}

// Round 12
// 130.313 us; speedup vs baseline: 3.1023x; 1.0216x over previous
//
#include <hip/hip_runtime.h>
#include <hip/hip_bf16.h>
#include <math.h>

#define NPOS 2048
#define CH   512
#define KATT 128
#define NHEAD 8

typedef __attribute__((ext_vector_type(8))) short short8;
typedef __attribute__((ext_vector_type(4))) float f32x4;

static __device__ __forceinline__ ushort f2bf(float f) {
  union { float f; unsigned u; } v; v.f = f;
  unsigned r = (v.u + 0x7FFFu + ((v.u >> 16) & 1u)) >> 16;
  return (ushort)r;
}
static __device__ __forceinline__ float bf2f(ushort u) {
  union { unsigned u; float f; } v; v.u = ((unsigned)u) << 16;
  return v.f;
}

// global -> LDS direct DMA, 16B per lane. LDS dest = base + lane*16 (linear).
static __device__ __forceinline__ void gl16(const void* g, void* l) {
  __builtin_amdgcn_global_load_lds(
      (const __attribute__((address_space(1))) unsigned int*)(uintptr_t)g,
      (__attribute__((address_space(3))) unsigned int*)(uintptr_t)l, 16, 0, 0);
}

// ---------------------------------------------------------------------------
// Fused prep: 1153 blocks.
//  bid<256     : GroupNorm stats (32 groups x 8 octants) -> part
//  256..1023   : convert wq|wk|wv fp32 -> bf16 (contiguous wqkv)
//  1024..1151  : permute+convert wp -> wppb[co][h*64+d] (LDS-coalesced)
//  1152        : pack biases
// ---------------------------------------------------------------------------
__global__ __launch_bounds__(256) void prep_k(const float* __restrict__ x,
    const float* __restrict__ wq, const float* __restrict__ wk,
    const float* __restrict__ wv, const float* __restrict__ wp,
    const float* __restrict__ bq, const float* __restrict__ bk,
    const float* __restrict__ bv, float* __restrict__ part,
    ushort* __restrict__ wqkv, ushort* __restrict__ wppb,
    float* __restrict__ bqkv) {
  const int bid = blockIdx.x;
  if (bid < 256) {
    const int b = bid;
    const float* xp = x + (b >> 3) * 32768 + (b & 7) * 4096;
    float s = 0.f, ss = 0.f;
    for (int i = threadIdx.x; i < 4096; i += 256) {
      float v = xp[i];
      s += v;
      ss += v * v;
    }
    __shared__ float rs[256], rq[256];
    rs[threadIdx.x] = s;
    rq[threadIdx.x] = ss;
    __syncthreads();
    for (int off = 128; off > 0; off >>= 1) {
      if (threadIdx.x < (unsigned)off) {
        rs[threadIdx.x] += rs[threadIdx.x + off];
        rq[threadIdx.x] += rq[threadIdx.x + off];
      }
      __syncthreads();
    }
    if (threadIdx.x == 0) {
      part[b * 2] = rs[0];
      part[b * 2 + 1] = rq[0];
    }
  } else if (bid < 1024) {
    const int wb = bid - 256;
    const int m = wb >> 8;
    const float* src = m == 0 ? wq : (m == 1 ? wk : wv);
    const int i = (wb & 255) * 1024 + threadIdx.x * 4;
    const float4 v = *(const float4*)(src + i);
    uint2 p;
    p.x = (unsigned)f2bf(v.x) | ((unsigned)f2bf(v.y) << 16);
    p.y = (unsigned)f2bf(v.z) | ((unsigned)f2bf(v.w) << 16);
    *(uint2*)(wqkv + m * 262144 + i) = p;
  } else if (bid < 1152) {
    __shared__ float lds[2048];
    const int co0 = (bid - 1024) * 4;
    for (int t = threadIdx.x; t < 2048; t += 256) lds[t] = wp[co0 * 512 + t];
    __syncthreads();
    ushort o8[8];
#pragma unroll
    for (int e = 0; e < 8; ++e) {
      const int jj = threadIdx.x * 8 + e;
      const int col = jj >> 9;
      const int sl = jj & 511;
      o8[e] = f2bf(lds[col * 512 + (sl & 63) * 8 + (sl >> 6)]);
    }
    *(uint4*)(wppb + co0 * 512 + threadIdx.x * 8) = *(uint4*)o8;
  } else {
    for (int i = threadIdx.x; i < 1536; i += 256)
      bqkv[i] = i < 512 ? bq[i] : (i < 1024 ? bk[i - 512] : bv[i - 1024]);
  }
}

// ---------------------------------------------------------------------------
// GroupNorm pass 2 + bf16 transpose: 512 blocks = 32 groups x 16 pos-chunks.
// ---------------------------------------------------------------------------
__global__ __launch_bounds__(256) void gn2_k(const float* __restrict__ x,
    const float* __restrict__ part, const float* __restrict__ gw,
    const float* __restrict__ gb, ushort* __restrict__ ht) {
  const int g = blockIdx.x >> 4;
  const int chunk = blockIdx.x & 15;
  float s = 0.f, ss = 0.f;
#pragma unroll
  for (int o = 0; o < 8; ++o) {
    s += part[(g * 8 + o) * 2];
    ss += part[(g * 8 + o) * 2 + 1];
  }
  const float inv_n = 1.f / 32768.f;
  const float mu = s * inv_n;
  const float var = ss * inv_n - mu * mu;
  const float rstd = rsqrtf(var + 1e-6f);

  const int half = threadIdx.x >> 7;
  const int pos = chunk * 128 + (threadIdx.x & 127);
  unsigned pk[4];
#pragma unroll
  for (int c2 = 0; c2 < 4; ++c2) {
    unsigned p = 0;
#pragma unroll
    for (int e = 0; e < 2; ++e) {
      const int cc = half * 8 + c2 * 2 + e;
      const int ch = g * 16 + cc;
      const float a = gw[ch] * rstd;
      const float v = x[ch * NPOS + pos] * a + (gb[ch] - mu * a);
      p |= ((unsigned)f2bf(v)) << (16 * e);
    }
    pk[c2] = p;
  }
  *(uint4*)(ht + pos * CH + g * 16 + half * 8) = make_uint4(pk[0], pk[1], pk[2], pk[3]);
}

// ---------------------------------------------------------------------------
// bf16 MFMA GEMM with global_load_lds staging (linear LDS dest, source-side
// swizzle; ds_read applies the same XOR -> cancels).
// MODE 0: fused QKV; cols 0..1023 -> qt/kt (fp32), cols 1024.. -> vtb (bf16).
// MODE 1: proj + residual (fp32 out).
// ---------------------------------------------------------------------------
template<int TM, int WN, int MODE>
__global__ __launch_bounds__(256) void mm_k(const ushort* __restrict__ A,
    const ushort* __restrict__ Bm, const float* __restrict__ bias,
    const float* __restrict__ resid, float* __restrict__ outF,
    ushort* __restrict__ outV) {
  constexpr int WM = 4 / WN;
  constexpr int FM = TM / (WM * 16);
  constexpr int FN = 64 / (WN * 16);
  __shared__ ushort As[TM * 64];
  __shared__ ushort Bs[64 * 64];
  const int mBase = blockIdx.x * TM;
  const int nBase = blockIdx.y * 64;
  const int tid = threadIdx.x;
  const int l = tid & 63;
  const int w = tid >> 6;
  const int wm = w / WN, wn = w % WN;
  const int sub8 = l >> 3;
  const int c16 = (l & 7) << 4;
  f32x4 acc[FM][FN] = {};

  for (int k0 = 0; k0 < 512; k0 += 64) {
#pragma unroll
    for (int c = 0; c < TM / 32; ++c) {
      const int r0 = w * (TM / 4) + c * 8;
      const int row = r0 + sub8;
      const int sc = c16 ^ ((row & 7) << 4);
      gl16(A + (mBase + row) * 512 + k0 + (sc >> 1), (char*)As + r0 * 128);
    }
#pragma unroll
    for (int c = 0; c < 2; ++c) {
      const int r0 = w * 16 + c * 8;
      const int row = r0 + sub8;
      const int sc = c16 ^ ((row & 7) << 4);
      gl16(Bm + (nBase + row) * 512 + k0 + (sc >> 1), (char*)Bs + r0 * 128);
    }
    __syncthreads();
#pragma unroll
    for (int ks = 0; ks < 2; ++ks) {
      const int kb = ks * 64 + ((l >> 4) << 4);
      short8 afr[FM], bfr[FN];
#pragma unroll
      for (int fm = 0; fm < FM; ++fm) {
        const int ra = wm * (FM * 16) + fm * 16 + (l & 15);
        afr[fm] = *(const short8*)((const char*)As + ra * 128 + (kb ^ ((ra & 7) << 4)));
      }
#pragma unroll
      for (int fn = 0; fn < FN; ++fn) {
        const int rb = wn * (FN * 16) + fn * 16 + (l & 15);
        bfr[fn] = *(const short8*)((const char*)Bs + rb * 128 + (kb ^ ((rb & 7) << 4)));
      }
#pragma unroll
      for (int fm = 0; fm < FM; ++fm)
#pragma unroll
        for (int fn = 0; fn < FN; ++fn)
          acc[fm][fn] = __builtin_amdgcn_mfma_f32_16x16x32_bf16(afr[fm], bfr[fn], acc[fm][fn], 0, 0, 0);
    }
    __syncthreads();
  }

#pragma unroll
  for (int fm = 0; fm < FM; ++fm)
#pragma unroll
    for (int fn = 0; fn < FN; ++fn) {
      const int col = nBase + wn * (FN * 16) + fn * 16 + (l & 15);
#pragma unroll
      for (int r = 0; r < 4; ++r) {
        const int rowm = mBase + wm * (FM * 16) + fm * 16 + ((l >> 4) << 2) + r;
        if (MODE == 0) {
          const float v = acc[fm][fn][r] + bias[col];
          if (col < 1024) {
            outF[(col >> 9) * (NPOS * CH) + rowm * CH + (col & 511)] = v;
          } else {
            outV[rowm * CH + (col & 511)] = f2bf(v);
          }
        } else {
          const int off = rowm * NPOS + col;
          outF[off] = acc[fm][fn][r] + bias[rowm] + resid[off];
        }
      }
    }
}

// ---------------------------------------------------------------------------
// Gather attention, valid-key compaction, V in bf16. One wave per
// (qpos, head), 4 independent waves/block, NO barriers (per-wave LDS).
// QK pass loop unrolled x2 (2x outstanding gathers).
// ---------------------------------------------------------------------------
__global__ __launch_bounds__(256) void attn_k(const float* __restrict__ qt,
    const float* __restrict__ kt, const ushort* __restrict__ vtb,
    const int* __restrict__ aidx, const int* __restrict__ vmask,
    ushort* __restrict__ ot) {
  __shared__ int ils[4][KATT];
  __shared__ float scs[4][KATT];
  __shared__ float prs[4][2 * KATT];
  const int w = threadIdx.x >> 6;
  const int lane = threadIdx.x & 63;
  const int p = blockIdx.x * 4 + w;  // p = qpos*8 + head
  const int hd = p & 7;
  const int qpos = p >> 3;
  const int quad = lane >> 2;
  const int sub = lane & 3;
  int* ils_w = ils[w];
  float* scs_w = scs[w];
  float* prs_w = prs[w];

  const float* qb = qt + qpos * CH + hd * 64;
  float4 qv[4];
#pragma unroll
  for (int t = 0; t < 4; ++t) qv[t] = *(const float4*)(qb + t * 16 + sub * 4);

  const int i0 = qpos * KATT + lane;
  const int idx0 = aidx[i0];
  const int idx1 = aidx[i0 + 64];
  const int m0 = vmask[i0];
  const int m1 = vmask[i0 + 64];

  // compact valid keys -> ils_w[0..nv)
  const unsigned long long b0 = __ballot(m0 != 0);
  const unsigned long long b1 = __ballot(m1 != 0);
  const int nv0 = __popcll(b0);
  const int nv = nv0 + __popcll(b1);
  const unsigned long long low = (1ull << lane) - 1ull;
  ils_w[lane] = 0;
  ils_w[lane + 64] = 0;
  if (m0) ils_w[__popcll(b0 & low)] = idx0;
  if (m1) ils_w[nv0 + __popcll(b1 & low)] = idx1;

  // QK over valid keys, 2 passes per iteration (more loads in flight)
  const int P = (nv + 15) >> 4;
  for (int p8 = 0; p8 < P; p8 += 2) {
    const int t0 = p8 * 16 + quad;
    const int t1 = t0 + 16;
    const bool has1 = (p8 + 1) < P;
    const int ki0 = ils_w[t0];
    const int ki1 = has1 ? ils_w[t1] : 0;
    const float* kr0 = kt + ki0 * CH + hd * 64;
    const float* kr1 = kt + ki1 * CH + hd * 64;
    float4 kc0[4], kc1[4];
#pragma unroll
    for (int tt = 0; tt < 4; ++tt) kc0[tt] = *(const float4*)(kr0 + tt * 16 + sub * 4);
#pragma unroll
    for (int tt = 0; tt < 4; ++tt) kc1[tt] = *(const float4*)(kr1 + tt * 16 + sub * 4);
    float s0 = 0.f, s1 = 0.f;
#pragma unroll
    for (int tt = 0; tt < 4; ++tt) {
      s0 += kc0[tt].x * qv[tt].x + kc0[tt].y * qv[tt].y + kc0[tt].z * qv[tt].z + kc0[tt].w * qv[tt].w;
      s1 += kc1[tt].x * qv[tt].x + kc1[tt].y * qv[tt].y + kc1[tt].z * qv[tt].z + kc1[tt].w * qv[tt].w;
    }
    s0 += __shfl_xor(s0, 1); s0 += __shfl_xor(s0, 2);
    s1 += __shfl_xor(s1, 1); s1 += __shfl_xor(s1, 2);
    if (sub == 0 && t0 < nv) scs_w[t0] = s0;
    if (sub == 0 && has1 && t1 < nv) scs_w[t1] = s1;
  }

  // softmax over the nv compacted scores
  float s0 = (lane < nv) ? scs_w[lane] : -INFINITY;
  float s1 = (lane + 64 < nv) ? scs_w[lane + 64] : -INFINITY;
  float mx = fmaxf(s0, s1);
#pragma unroll
  for (int off = 32; off > 0; off >>= 1) mx = fmaxf(mx, __shfl_xor(mx, off));
  const float e0 = __expf(s0 - mx);
  const float e1 = __expf(s1 - mx);
  float lsum = (lane < nv ? e0 : 0.f) + (lane + 64 < nv ? e1 : 0.f);
#pragma unroll
  for (int off = 32; off > 0; off >>= 1) lsum += __shfl_xor(lsum, off);
  const float inv = 1.f / lsum;

  if (lane < nv) {
    prs_w[2 * lane] = e0 * inv;
    prs_w[2 * lane + 1] = __int_as_float(ils_w[lane]);
  }
  if (lane + 64 < nv) {
    prs_w[2 * (lane + 64)] = e1 * inv;
    prs_w[2 * (lane + 64) + 1] = __int_as_float(ils_w[lane + 64]);
  }

  // PV over valid keys; lane = d; V bf16 (half the gather bytes)
  const ushort* vb = vtb + hd * 64 + lane;
  float o = 0.f;
  int kk = 0;
  for (; kk + 8 <= nv; kk += 8) {
    const float4 c0 = *(const float4*)&prs_w[2 * kk];
    const float4 c1 = *(const float4*)&prs_w[2 * kk + 4];
    const float4 c2 = *(const float4*)&prs_w[2 * kk + 8];
    const float4 c3 = *(const float4*)&prs_w[2 * kk + 12];
    float vv[8];
    vv[0] = bf2f(vb[__float_as_int(c0.y) * CH]);
    vv[1] = bf2f(vb[__float_as_int(c0.w) * CH]);
    vv[2] = bf2f(vb[__float_as_int(c1.y) * CH]);
    vv[3] = bf2f(vb[__float_as_int(c1.w) * CH]);
    vv[4] = bf2f(vb[__float_as_int(c2.y) * CH]);
    vv[5] = bf2f(vb[__float_as_int(c2.w) * CH]);
    vv[6] = bf2f(vb[__float_as_int(c3.y) * CH]);
    vv[7] = bf2f(vb[__float_as_int(c3.w) * CH]);
    o += c0.x * vv[0] + c0.z * vv[1] + c1.x * vv[2] + c1.z * vv[3] +
         c2.x * vv[4] + c2.z * vv[5] + c3.x * vv[6] + c3.z * vv[7];
  }
  for (; kk < nv; ++kk) {
    const float2 c = *(const float2*)&prs_w[2 * kk];
    o += c.x * bf2f(vb[__float_as_int(c.y) * CH]);
  }
  ot[qpos * CH + hd * 64 + lane] = f2bf(o);
}

// ---------------------------------------------------------------------------
extern "C" void kernel_launch(void* const* d_in, const int* in_sizes, int n_in,
                              void* d_out, int out_size, void* d_ws, size_t ws_size,
                              hipStream_t stream) {
  const float* x    = (const float*)d_in[0];
  const int* vmask  = (const int*)d_in[1];
  const int* aidx   = (const int*)d_in[2];
  const float* gnw  = (const float*)d_in[3];
  const float* gnb  = (const float*)d_in[4];
  const float* wq   = (const float*)d_in[5];
  const float* bq   = (const float*)d_in[6];
  const float* wk   = (const float*)d_in[7];
  const float* bk   = (const float*)d_in[8];
  const float* wv   = (const float*)d_in[9];
  const float* bv   = (const float*)d_in[10];
  const float* wp   = (const float*)d_in[11];
  const float* bp   = (const float*)d_in[12];
  float* out = (float*)d_out;

  char* ws = (char*)d_ws;
  ushort* ht    = (ushort*)(ws);                          // 2 MB (NPOS x CH bf16)
  float*  qt    = (float*)(ws + (2u  << 20));             // 4 MB (NPOS x CH f32)
  float*  kt    = (float*)(ws + (6u  << 20));             // 4 MB (NPOS x CH f32)
  ushort* vtb   = (ushort*)(ws + (10u << 20));            // 2 MB (NPOS x CH bf16)
  ushort* ot    = (ushort*)(ws + (14u << 20));            // 2 MB (NPOS x CH bf16)
  ushort* wqkv  = (ushort*)(ws + (16u << 20));            // 1.5 MB (1536 x 512 bf16)
  ushort* wppb  = (ushort*)(ws + (17u << 20) + (512u << 10));  // 0.5 MB
  float*  bqkv  = (float*)(ws + (18u << 20));             // 6 KB
  float*  part  = (float*)(ws + (18u << 20) + (32u << 10));    // 2 KB
  // total ~18.1 MB

  prep_k<<<1153, 256, 0, stream>>>(x, wq, wk, wv, wp, bq, bk, bv,
                                   part, wqkv, wppb, bqkv);
  gn2_k<<<512, 256, 0, stream>>>(x, part, gnw, gnb, ht);

  // fused QKV: A=ht (2048x512), B=wqkv (1536x512) -> 768 blocks
  mm_k<64, 2, 0><<<dim3(NPOS / 64, 1536 / 64), 256, 0, stream>>>(
      ht, wqkv, bqkv, nullptr, qt, vtb);

  attn_k<<<(NPOS * NHEAD) / 4, 256, 0, stream>>>(qt, kt, vtb, aidx, vmask, ot);

  // proj: A=wppb (512x512), B=ot (2048x512) -> 512 blocks
  mm_k<32, 4, 1><<<dim3(CH / 32, NPOS / 64), 256, 0, stream>>>(
      wppb, ot, bp, x, out, nullptr);
}

// Round 14
// 129.593 us; speedup vs baseline: 3.1195x; 1.0056x over previous
//
#include <hip/hip_runtime.h>
#include <hip/hip_bf16.h>
#include <math.h>

#define NPOS 2048
#define CH   512
#define KATT 128
#define NHEAD 8

typedef __attribute__((ext_vector_type(8))) short short8;
typedef __attribute__((ext_vector_type(4))) float f32x4;

static __device__ __forceinline__ ushort f2bf(float f) {
  union { float f; unsigned u; } v; v.f = f;
  unsigned r = (v.u + 0x7FFFu + ((v.u >> 16) & 1u)) >> 16;
  return (ushort)r;
}
static __device__ __forceinline__ float bf2f(ushort u) {
  union { unsigned u; float f; } v; v.u = ((unsigned)u) << 16;
  return v.f;
}

// global -> LDS direct DMA, 16B per lane. LDS dest = base + lane*16 (linear).
static __device__ __forceinline__ void gl16(const void* g, void* l) {
  __builtin_amdgcn_global_load_lds(
      (const __attribute__((address_space(1))) unsigned int*)(uintptr_t)g,
      (__attribute__((address_space(3))) unsigned int*)(uintptr_t)l, 16, 0, 0);
}

// ---------------------------------------------------------------------------
// Fused prep: 1153 blocks.
//  bid<256     : GroupNorm stats (32 groups x 8 octants) -> part
//  256..1023   : convert wq|wk|wv fp32 -> bf16 (contiguous wqkv)
//  1024..1151  : permute+convert wp -> wppb[co][h*64+d] (LDS-coalesced)
//  1152        : pack biases
// ---------------------------------------------------------------------------
__global__ __launch_bounds__(256) void prep_k(const float* __restrict__ x,
    const float* __restrict__ wq, const float* __restrict__ wk,
    const float* __restrict__ wv, const float* __restrict__ wp,
    const float* __restrict__ bq, const float* __restrict__ bk,
    const float* __restrict__ bv, float* __restrict__ part,
    ushort* __restrict__ wqkv, ushort* __restrict__ wppb,
    float* __restrict__ bqkv) {
  const int bid = blockIdx.x;
  if (bid < 256) {
    const int b = bid;
    const float* xp = x + (b >> 3) * 32768 + (b & 7) * 4096;
    float s = 0.f, ss = 0.f;
    for (int i = threadIdx.x; i < 4096; i += 256) {
      float v = xp[i];
      s += v;
      ss += v * v;
    }
    __shared__ float rs[256], rq[256];
    rs[threadIdx.x] = s;
    rq[threadIdx.x] = ss;
    __syncthreads();
    for (int off = 128; off > 0; off >>= 1) {
      if (threadIdx.x < (unsigned)off) {
        rs[threadIdx.x] += rs[threadIdx.x + off];
        rq[threadIdx.x] += rq[threadIdx.x + off];
      }
      __syncthreads();
    }
    if (threadIdx.x == 0) {
      part[b * 2] = rs[0];
      part[b * 2 + 1] = rq[0];
    }
  } else if (bid < 1024) {
    const int wb = bid - 256;
    const int m = wb >> 8;
    const float* src = m == 0 ? wq : (m == 1 ? wk : wv);
    const int i = (wb & 255) * 1024 + threadIdx.x * 4;
    const float4 v = *(const float4*)(src + i);
    uint2 p;
    p.x = (unsigned)f2bf(v.x) | ((unsigned)f2bf(v.y) << 16);
    p.y = (unsigned)f2bf(v.z) | ((unsigned)f2bf(v.w) << 16);
    *(uint2*)(wqkv + m * 262144 + i) = p;
  } else if (bid < 1152) {
    __shared__ float lds[2048];
    const int co0 = (bid - 1024) * 4;
    for (int t = threadIdx.x; t < 2048; t += 256) lds[t] = wp[co0 * 512 + t];
    __syncthreads();
    ushort o8[8];
#pragma unroll
    for (int e = 0; e < 8; ++e) {
      const int jj = threadIdx.x * 8 + e;
      const int col = jj >> 9;
      const int sl = jj & 511;
      o8[e] = f2bf(lds[col * 512 + (sl & 63) * 8 + (sl >> 6)]);
    }
    *(uint4*)(wppb + co0 * 512 + threadIdx.x * 8) = *(uint4*)o8;
  } else {
    for (int i = threadIdx.x; i < 1536; i += 256)
      bqkv[i] = i < 512 ? bq[i] : (i < 1024 ? bk[i - 512] : bv[i - 1024]);
  }
}

// ---------------------------------------------------------------------------
// GroupNorm pass 2 + bf16 transpose: 512 blocks = 32 groups x 16 pos-chunks.
// ---------------------------------------------------------------------------
__global__ __launch_bounds__(256) void gn2_k(const float* __restrict__ x,
    const float* __restrict__ part, const float* __restrict__ gw,
    const float* __restrict__ gb, ushort* __restrict__ ht) {
  const int g = blockIdx.x >> 4;
  const int chunk = blockIdx.x & 15;
  float s = 0.f, ss = 0.f;
#pragma unroll
  for (int o = 0; o < 8; ++o) {
    s += part[(g * 8 + o) * 2];
    ss += part[(g * 8 + o) * 2 + 1];
  }
  const float inv_n = 1.f / 32768.f;
  const float mu = s * inv_n;
  const float var = ss * inv_n - mu * mu;
  const float rstd = rsqrtf(var + 1e-6f);

  const int half = threadIdx.x >> 7;
  const int pos = chunk * 128 + (threadIdx.x & 127);
  unsigned pk[4];
#pragma unroll
  for (int c2 = 0; c2 < 4; ++c2) {
    unsigned p = 0;
#pragma unroll
    for (int e = 0; e < 2; ++e) {
      const int cc = half * 8 + c2 * 2 + e;
      const int ch = g * 16 + cc;
      const float a = gw[ch] * rstd;
      const float v = x[ch * NPOS + pos] * a + (gb[ch] - mu * a);
      p |= ((unsigned)f2bf(v)) << (16 * e);
    }
    pk[c2] = p;
  }
  *(uint4*)(ht + pos * CH + g * 16 + half * 8) = make_uint4(pk[0], pk[1], pk[2], pk[3]);
}

// ---------------------------------------------------------------------------
// bf16 MFMA GEMM, double-buffered LDS with global_load_lds staging.
// 2-phase schedule (T3-min): stage NEXT K-tile, compute CURRENT, then one
// __syncthreads per K-step (its implicit vmcnt(0) lands the next tile after
// compute has hidden the DMA latency). Source-side swizzle (involution with
// the ds_read XOR).
// MODE 0: fused QKV; cols 0..1023 -> qt/kt (fp32), cols 1024.. -> vtb (bf16).
// MODE 1: proj + residual (fp32 out).
// ---------------------------------------------------------------------------
template<int TM, int WN, int MODE>
__global__ __launch_bounds__(256) void mm_k(const ushort* __restrict__ A,
    const ushort* __restrict__ Bm, const float* __restrict__ bias,
    const float* __restrict__ resid, float* __restrict__ outF,
    ushort* __restrict__ outV) {
  constexpr int WM = 4 / WN;
  constexpr int FM = TM / (WM * 16);
  constexpr int FN = 64 / (WN * 16);
  __shared__ ushort As[2][TM * 64];
  __shared__ ushort Bs[2][64 * 64];
  const int mBase = blockIdx.x * TM;
  const int nBase = blockIdx.y * 64;
  const int tid = threadIdx.x;
  const int l = tid & 63;
  const int w = tid >> 6;
  const int wm = w / WN, wn = w % WN;
  const int sub8 = l >> 3;        // row within 8-row DMA call
  const int c16 = (l & 7) << 4;   // byte col within 128B row
  f32x4 acc[FM][FN] = {};

#define MM_STAGE(buf, kk0)                                                  \
  {                                                                         \
    _Pragma("unroll")                                                       \
    for (int c = 0; c < TM / 32; ++c) {                                     \
      const int r0 = w * (TM / 4) + c * 8;                                  \
      const int row = r0 + sub8;                                            \
      const int sc = c16 ^ ((row & 7) << 4);                                \
      gl16(A + (mBase + row) * 512 + (kk0) + (sc >> 1),                     \
           (char*)As[buf] + r0 * 128);                                      \
    }                                                                       \
    _Pragma("unroll")                                                       \
    for (int c = 0; c < 2; ++c) {                                           \
      const int r0 = w * 16 + c * 8;                                        \
      const int row = r0 + sub8;                                            \
      const int sc = c16 ^ ((row & 7) << 4);                                \
      gl16(Bm + (nBase + row) * 512 + (kk0) + (sc >> 1),                    \
           (char*)Bs[buf] + r0 * 128);                                      \
    }                                                                       \
  }

  MM_STAGE(0, 0);
  __syncthreads();  // implicit vmcnt(0): buf0 ready
  int cur = 0;
  for (int t = 0; t < 8; ++t) {
    if (t < 7) MM_STAGE(cur ^ 1, (t + 1) * 64);  // issue next tile's DMAs
#pragma unroll
    for (int ks = 0; ks < 2; ++ks) {
      const int kb = ks * 64 + ((l >> 4) << 4);
      short8 afr[FM], bfr[FN];
#pragma unroll
      for (int fm = 0; fm < FM; ++fm) {
        const int ra = wm * (FM * 16) + fm * 16 + (l & 15);
        afr[fm] = *(const short8*)((const char*)As[cur] + ra * 128 + (kb ^ ((ra & 7) << 4)));
      }
#pragma unroll
      for (int fn = 0; fn < FN; ++fn) {
        const int rb = wn * (FN * 16) + fn * 16 + (l & 15);
        bfr[fn] = *(const short8*)((const char*)Bs[cur] + rb * 128 + (kb ^ ((rb & 7) << 4)));
      }
#pragma unroll
      for (int fm = 0; fm < FM; ++fm)
#pragma unroll
        for (int fn = 0; fn < FN; ++fn)
          acc[fm][fn] = __builtin_amdgcn_mfma_f32_16x16x32_bf16(afr[fm], bfr[fn], acc[fm][fn], 0, 0, 0);
    }
    __syncthreads();  // vmcnt(0) drain: next buf staged; LDS reads done
    cur ^= 1;
  }
#undef MM_STAGE

#pragma unroll
  for (int fm = 0; fm < FM; ++fm)
#pragma unroll
    for (int fn = 0; fn < FN; ++fn) {
      const int col = nBase + wn * (FN * 16) + fn * 16 + (l & 15);
#pragma unroll
      for (int r = 0; r < 4; ++r) {
        const int rowm = mBase + wm * (FM * 16) + fm * 16 + ((l >> 4) << 2) + r;
        if (MODE == 0) {
          const float v = acc[fm][fn][r] + bias[col];
          if (col < 1024) {
            outF[(col >> 9) * (NPOS * CH) + rowm * CH + (col & 511)] = v;
          } else {
            outV[rowm * CH + (col & 511)] = f2bf(v);
          }
        } else {
          const int off = rowm * NPOS + col;
          outF[off] = acc[fm][fn][r] + bias[rowm] + resid[off];
        }
      }
    }
}

// ---------------------------------------------------------------------------
// Gather attention, valid-key compaction, V in bf16. One wave per
// (qpos, head), 4 independent waves/block, NO barriers (per-wave LDS).
// QK pass loop unrolled x2 (2x outstanding gathers).
// ---------------------------------------------------------------------------
__global__ __launch_bounds__(256) void attn_k(const float* __restrict__ qt,
    const float* __restrict__ kt, const ushort* __restrict__ vtb,
    const int* __restrict__ aidx, const int* __restrict__ vmask,
    ushort* __restrict__ ot) {
  __shared__ int ils[4][KATT];
  __shared__ float scs[4][KATT];
  __shared__ float prs[4][2 * KATT];
  const int w = threadIdx.x >> 6;
  const int lane = threadIdx.x & 63;
  const int p = blockIdx.x * 4 + w;  // p = qpos*8 + head
  const int hd = p & 7;
  const int qpos = p >> 3;
  const int quad = lane >> 2;
  const int sub = lane & 3;
  int* ils_w = ils[w];
  float* scs_w = scs[w];
  float* prs_w = prs[w];

  const float* qb = qt + qpos * CH + hd * 64;
  float4 qv[4];
#pragma unroll
  for (int t = 0; t < 4; ++t) qv[t] = *(const float4*)(qb + t * 16 + sub * 4);

  const int i0 = qpos * KATT + lane;
  const int idx0 = aidx[i0];
  const int idx1 = aidx[i0 + 64];
  const int m0 = vmask[i0];
  const int m1 = vmask[i0 + 64];

  // compact valid keys -> ils_w[0..nv)
  const unsigned long long b0 = __ballot(m0 != 0);
  const unsigned long long b1 = __ballot(m1 != 0);
  const int nv0 = __popcll(b0);
  const int nv = nv0 + __popcll(b1);
  const unsigned long long low = (1ull << lane) - 1ull;
  ils_w[lane] = 0;
  ils_w[lane + 64] = 0;
  if (m0) ils_w[__popcll(b0 & low)] = idx0;
  if (m1) ils_w[nv0 + __popcll(b1 & low)] = idx1;

  // QK over valid keys, 2 passes per iteration (more loads in flight)
  const int P = (nv + 15) >> 4;
  for (int p8 = 0; p8 < P; p8 += 2) {
    const int t0 = p8 * 16 + quad;
    const int t1 = t0 + 16;
    const bool has1 = (p8 + 1) < P;
    const int ki0 = ils_w[t0];
    const int ki1 = has1 ? ils_w[t1] : 0;
    const float* kr0 = kt + ki0 * CH + hd * 64;
    const float* kr1 = kt + ki1 * CH + hd * 64;
    float4 kc0[4], kc1[4];
#pragma unroll
    for (int tt = 0; tt < 4; ++tt) kc0[tt] = *(const float4*)(kr0 + tt * 16 + sub * 4);
#pragma unroll
    for (int tt = 0; tt < 4; ++tt) kc1[tt] = *(const float4*)(kr1 + tt * 16 + sub * 4);
    float s0 = 0.f, s1 = 0.f;
#pragma unroll
    for (int tt = 0; tt < 4; ++tt) {
      s0 += kc0[tt].x * qv[tt].x + kc0[tt].y * qv[tt].y + kc0[tt].z * qv[tt].z + kc0[tt].w * qv[tt].w;
      s1 += kc1[tt].x * qv[tt].x + kc1[tt].y * qv[tt].y + kc1[tt].z * qv[tt].z + kc1[tt].w * qv[tt].w;
    }
    s0 += __shfl_xor(s0, 1); s0 += __shfl_xor(s0, 2);
    s1 += __shfl_xor(s1, 1); s1 += __shfl_xor(s1, 2);
    if (sub == 0 && t0 < nv) scs_w[t0] = s0;
    if (sub == 0 && has1 && t1 < nv) scs_w[t1] = s1;
  }

  // softmax over the nv compacted scores
  float s0 = (lane < nv) ? scs_w[lane] : -INFINITY;
  float s1 = (lane + 64 < nv) ? scs_w[lane + 64] : -INFINITY;
  float mx = fmaxf(s0, s1);
#pragma unroll
  for (int off = 32; off > 0; off >>= 1) mx = fmaxf(mx, __shfl_xor(mx, off));
  const float e0 = __expf(s0 - mx);
  const float e1 = __expf(s1 - mx);
  float lsum = (lane < nv ? e0 : 0.f) + (lane + 64 < nv ? e1 : 0.f);
#pragma unroll
  for (int off = 32; off > 0; off >>= 1) lsum += __shfl_xor(lsum, off);
  const float inv = 1.f / lsum;

  if (lane < nv) {
    prs_w[2 * lane] = e0 * inv;
    prs_w[2 * lane + 1] = __int_as_float(ils_w[lane]);
  }
  if (lane + 64 < nv) {
    prs_w[2 * (lane + 64)] = e1 * inv;
    prs_w[2 * (lane + 64) + 1] = __int_as_float(ils_w[lane + 64]);
  }

  // PV over valid keys; lane = d; V bf16 (half the gather bytes)
  const ushort* vb = vtb + hd * 64 + lane;
  float o = 0.f;
  int kk = 0;
  for (; kk + 8 <= nv; kk += 8) {
    const float4 c0 = *(const float4*)&prs_w[2 * kk];
    const float4 c1 = *(const float4*)&prs_w[2 * kk + 4];
    const float4 c2 = *(const float4*)&prs_w[2 * kk + 8];
    const float4 c3 = *(const float4*)&prs_w[2 * kk + 12];
    float vv[8];
    vv[0] = bf2f(vb[__float_as_int(c0.y) * CH]);
    vv[1] = bf2f(vb[__float_as_int(c0.w) * CH]);
    vv[2] = bf2f(vb[__float_as_int(c1.y) * CH]);
    vv[3] = bf2f(vb[__float_as_int(c1.w) * CH]);
    vv[4] = bf2f(vb[__float_as_int(c2.y) * CH]);
    vv[5] = bf2f(vb[__float_as_int(c2.w) * CH]);
    vv[6] = bf2f(vb[__float_as_int(c3.y) * CH]);
    vv[7] = bf2f(vb[__float_as_int(c3.w) * CH]);
    o += c0.x * vv[0] + c0.z * vv[1] + c1.x * vv[2] + c1.z * vv[3] +
         c2.x * vv[4] + c2.z * vv[5] + c3.x * vv[6] + c3.z * vv[7];
  }
  for (; kk < nv; ++kk) {
    const float2 c = *(const float2*)&prs_w[2 * kk];
    o += c.x * bf2f(vb[__float_as_int(c.y) * CH]);
  }
  ot[qpos * CH + hd * 64 + lane] = f2bf(o);
}

// ---------------------------------------------------------------------------
extern "C" void kernel_launch(void* const* d_in, const int* in_sizes, int n_in,
                              void* d_out, int out_size, void* d_ws, size_t ws_size,
                              hipStream_t stream) {
  const float* x    = (const float*)d_in[0];
  const int* vmask  = (const int*)d_in[1];
  const int* aidx   = (const int*)d_in[2];
  const float* gnw  = (const float*)d_in[3];
  const float* gnb  = (const float*)d_in[4];
  const float* wq   = (const float*)d_in[5];
  const float* bq   = (const float*)d_in[6];
  const float* wk   = (const float*)d_in[7];
  const float* bk   = (const float*)d_in[8];
  const float* wv   = (const float*)d_in[9];
  const float* bv   = (const float*)d_in[10];
  const float* wp   = (const float*)d_in[11];
  const float* bp   = (const float*)d_in[12];
  float* out = (float*)d_out;

  char* ws = (char*)d_ws;
  ushort* ht    = (ushort*)(ws);                          // 2 MB (NPOS x CH bf16)
  float*  qt    = (float*)(ws + (2u  << 20));             // 4 MB (NPOS x CH f32)
  float*  kt    = (float*)(ws + (6u  << 20));             // 4 MB (NPOS x CH f32)
  ushort* vtb   = (ushort*)(ws + (10u << 20));            // 2 MB (NPOS x CH bf16)
  ushort* ot    = (ushort*)(ws + (14u << 20));            // 2 MB (NPOS x CH bf16)
  ushort* wqkv  = (ushort*)(ws + (16u << 20));            // 1.5 MB (1536 x 512 bf16)
  ushort* wppb  = (ushort*)(ws + (17u << 20) + (512u << 10));  // 0.5 MB
  float*  bqkv  = (float*)(ws + (18u << 20));             // 6 KB
  float*  part  = (float*)(ws + (18u << 20) + (32u << 10));    // 2 KB
  // total ~18.1 MB

  prep_k<<<1153, 256, 0, stream>>>(x, wq, wk, wv, wp, bq, bk, bv,
                                   part, wqkv, wppb, bqkv);
  gn2_k<<<512, 256, 0, stream>>>(x, part, gnw, gnb, ht);

  // fused QKV: A=ht (2048x512), B=wqkv (1536x512) -> 1536 blocks (6/CU)
  mm_k<32, 2, 0><<<dim3(NPOS / 32, 1536 / 64), 256, 0, stream>>>(
      ht, wqkv, bqkv, nullptr, qt, vtb);

  attn_k<<<(NPOS * NHEAD) / 4, 256, 0, stream>>>(qt, kt, vtb, aidx, vmask, ot);

  // proj: A=wppb (512x512), B=ot (2048x512) -> 512 blocks
  mm_k<32, 4, 1><<<dim3(CH / 32, NPOS / 64), 256, 0, stream>>>(
      wppb, ot, bp, x, out, nullptr);
}